// Round 9
// baseline (350.225 us; speedup 1.0000x reference)
//
#include <hip/hip_runtime.h>
#include <hip/hip_bf16.h>
#include <math.h>

#define N_USERS_C 100000
#define BK_SHIFT 9
#define BK_NODES 512
// hot global atomic counters padded to one per 64B L2 line (16 ints)
#define CPAD 16

typedef __bf16 bf8_t __attribute__((ext_vector_type(8)));
typedef float f32x4 __attribute__((ext_vector_type(4)));

__device__ __forceinline__ unsigned int pack_bf16(float a, float b) {
    __hip_bfloat16 ha = __float2bfloat16(a), hb = __float2bfloat16(b);
    return ((unsigned int)(*(unsigned short*)&hb) << 16) | (unsigned int)(*(unsigned short*)&ha);
}
__device__ __forceinline__ unsigned short bf16_1(float a) {
    __hip_bfloat16 ha = __float2bfloat16(a);
    return *(unsigned short*)&ha;
}
__device__ __forceinline__ float bf_lo(unsigned int u) { return __uint_as_float(u << 16); }
__device__ __forceinline__ float bf_hi(unsigned int u) { return __uint_as_float(u & 0xffff0000u); }

#define ACC8(uu) { acc[0] += bf_lo(uu.x); acc[1] += bf_hi(uu.x); \
                   acc[2] += bf_lo(uu.y); acc[3] += bf_hi(uu.y); \
                   acc[4] += bf_lo(uu.z); acc[5] += bf_hi(uu.z); \
                   acc[6] += bf_lo(uu.w); acc[7] += bf_hi(uu.w); }

// ------- merged: bucket histogram (4096 edges/blk) || x->bf16 || W1/W2 bf16-pair pack -------
__global__ __launch_bounds__(512) void k_pre(const int* __restrict__ dst, int* __restrict__ chist,
                                             const float* __restrict__ x, unsigned int* __restrict__ xb,
                                             const float* __restrict__ W1, const float* __restrict__ W2,
                                             unsigned int* __restrict__ w1p, unsigned int* __restrict__ w2p,
                                             int E, int nbk, int EB2, int n2, int XB) {
    __shared__ int lcnt[BK_NODES];
    const int bid = blockIdx.x;
    const int t = threadIdx.x;
    if (bid < EB2) {
        if (t < nbk) lcnt[t] = 0;
        __syncthreads();
        int e0 = bid * 4096;
        #pragma unroll
        for (int j = 0; j < 8; ++j) {
            int e = e0 + j * 512 + t;
            if (e < E) atomicAdd(&lcnt[dst[e] >> BK_SHIFT], 1);
        }
        __syncthreads();
        if (t < nbk && lcnt[t]) atomicAdd(&chist[t * CPAD], lcnt[t]);
    } else if (bid < EB2 + XB) {
        int base = (bid - EB2) * 2048;
        #pragma unroll
        for (int j = 0; j < 4; ++j) {
            int i = base + j * 512 + t;
            if (i < n2) {
                float2 v = ((const float2*)x)[i];
                xb[i] = pack_bf16(v.x, v.y);
            }
        }
    } else if (bid == EB2 + XB) {
        // pack W1^T: w1p[n*32+kp] = bf16(W1[2kp][n]) | bf16(W1[2kp+1][n])<<16 ; n<128, kp<32
        #pragma unroll
        for (int j = 0; j < 8; ++j) {
            int i = j * 512 + t;
            int kp = i >> 7, n = i & 127;
            w1p[n * 32 + kp] = pack_bf16(W1[(size_t)(2 * kp) * 128 + n],
                                         W1[(size_t)(2 * kp + 1) * 128 + n]);
        }
    } else {
        // pack W2^T: w2p[n*64+kp] ; n<64, kp<64
        #pragma unroll
        for (int j = 0; j < 8; ++j) {
            int i = j * 512 + t;
            int kp = i >> 6, n = i & 63;
            w2p[n * 64 + kp] = pack_bf16(W2[(size_t)(2 * kp) * 64 + n],
                                         W2[(size_t)(2 * kp + 1) * 64 + n]);
        }
    }
}

// ---------------- pass 1: counting sort, 4096 edges/block, local chist scan ----------------
__global__ __launch_bounds__(512) void k_bin(const int* __restrict__ src,
                                             const int* __restrict__ dst,
                                             const int* __restrict__ chist,
                                             int* __restrict__ bcursor0,
                                             int* __restrict__ pairBuf, int E, int nbk) {
    __shared__ int lcnt[BK_NODES];
    __shared__ int lofs[BK_NODES];
    __shared__ int delta[BK_NODES];
    __shared__ int waveSum[8];
    __shared__ int sPack[4096];
    __shared__ unsigned short sBkt[4096];
    const int t = threadIdx.x;
    const int lane = t & 63;
    const int w = t >> 6;
    const int e0 = blockIdx.x * 4096;
    if (t < nbk) lcnt[t] = 0;
    __syncthreads();

    int mySrc[8], myB[8], myDl[8];
    #pragma unroll
    for (int j = 0; j < 8; ++j) {
        int e = e0 + j * 512 + t;
        if (e < E) {
            int sv = src[e], dv = dst[e];
            mySrc[j] = sv; myB[j] = dv >> BK_SHIFT; myDl[j] = dv & (BK_NODES - 1);
            atomicAdd(&lcnt[myB[j]], 1);
        } else myB[j] = -1;
    }
    __syncthreads();

    // wave-shuffle exclusive scan over lcnt, and local scan of chist for base
    int v = (t < nbk) ? lcnt[t] : 0;
    int inc = v;
    #pragma unroll
    for (int off = 1; off < 64; off <<= 1) {
        int n = __shfl_up(inc, off);
        if (lane >= off) inc += n;
    }
    if (lane == 63) waveSum[w] = inc;
    int cv = (t < nbk) ? chist[t * CPAD] : 0;   // global bucket count (padded)
    int cinc = cv;
    #pragma unroll
    for (int off = 1; off < 64; off <<= 1) {
        int n = __shfl_up(cinc, off);
        if (lane >= off) cinc += n;
    }
    __shared__ int cWaveSum[8];
    if (lane == 63) cWaveSum[w] = cinc;
    __syncthreads();
    int wp = 0, cwp = 0;
    #pragma unroll
    for (int i = 0; i < 8; ++i) {
        wp += (i < w) ? waveSum[i] : 0;
        cwp += (i < w) ? cWaveSum[i] : 0;
    }
    int ex = wp + inc - v;         // exclusive prefix of local counts
    int cbase = cwp + cinc - cv;   // global bucket base (exclusive scan of chist)
    if (t < nbk) {
        lofs[t] = ex;
        int gb = cbase + ((v > 0) ? atomicAdd(&bcursor0[t * CPAD], v) : 0);
        delta[t] = gb - ex;
    }
    __syncthreads();

    #pragma unroll
    for (int j = 0; j < 8; ++j) {
        if (myB[j] >= 0) {
            int p = atomicAdd(&lofs[myB[j]], 1);
            sPack[p] = mySrc[j] | (myDl[j] << 18);   // src < 2^18
            sBkt[p] = (unsigned short)myB[j];
        }
    }
    __syncthreads();
    int total = (E - e0 < 4096) ? (E - e0) : 4096;
    for (int i = t; i < total; i += 512)
        pairBuf[delta[sBkt[i]] + i] = sPack[i];
}

// ------- pass 2: per-bucket rowstart/dinv + csr scatter + xb pre-scale by dinv -------
// latency-critical loops batched 4-deep (293 blocks -> ~1 block/CU, nothing else hides latency)
__global__ __launch_bounds__(512) void k_bscatter(const int* __restrict__ pairBuf,
                                                  const int* __restrict__ chist,
                                                  int* __restrict__ rowstart,
                                                  float* __restrict__ dinv,
                                                  int* __restrict__ csr,
                                                  unsigned int* __restrict__ xb,
                                                  int N, int E, int nbk) {
    const int b = blockIdx.x;
    const int n0 = b << BK_SHIFT;
    int nn = N - n0; if (nn > BK_NODES) nn = BK_NODES;
    __shared__ int hist[BK_NODES];
    __shared__ int curs[BK_NODES];
    __shared__ float sdv[BK_NODES];
    __shared__ int waveSum[8];
    __shared__ int sE0, sE1;
    const int t = threadIdx.x;
    const int lane = t & 63;
    const int w = t >> 6;

    // local exclusive scan of chist -> this bucket's [e0,e1)
    {
        int cv = (t < nbk) ? chist[t * CPAD] : 0;
        int cinc = cv;
        #pragma unroll
        for (int off = 1; off < 64; off <<= 1) {
            int n = __shfl_up(cinc, off);
            if (lane >= off) cinc += n;
        }
        if (lane == 63) waveSum[w] = cinc;
        if (t < nn) hist[t] = 0;
        __syncthreads();
        int cwp = 0;
        #pragma unroll
        for (int i = 0; i < 8; ++i) cwp += (i < w) ? waveSum[i] : 0;
        if (t == b) { sE0 = cwp + cinc - cv; sE1 = cwp + cinc; }
    }
    __syncthreads();
    const int e0 = sE0, e1 = sE1;

    {
        int e = e0 + t;
        for (; e + 1536 < e1; e += 2048) {
            int p0 = pairBuf[e], p1 = pairBuf[e + 512];
            int p2 = pairBuf[e + 1024], p3 = pairBuf[e + 1536];
            atomicAdd(&hist[p0 >> 18], 1);
            atomicAdd(&hist[p1 >> 18], 1);
            atomicAdd(&hist[p2 >> 18], 1);
            atomicAdd(&hist[p3 >> 18], 1);
        }
        for (; e < e1; e += 512)
            atomicAdd(&hist[pairBuf[e] >> 18], 1);
    }
    __syncthreads();

    int v = (t < nn) ? hist[t] : 0;
    int inc = v;
    #pragma unroll
    for (int off = 1; off < 64; off <<= 1) {
        int n = __shfl_up(inc, off);
        if (lane >= off) inc += n;
    }
    if (lane == 63) waveSum[w] = inc;
    __syncthreads();
    int wp = 0;
    #pragma unroll
    for (int i = 0; i < 8; ++i) wp += (i < w) ? waveSum[i] : 0;
    int ex = wp + inc - v;
    if (t < nn) {
        int r = e0 + ex;
        rowstart[n0 + t] = r;
        curs[t] = r;
        float dv = rsqrtf((float)(v + 1));
        dinv[n0 + t] = dv;
        sdv[t] = dv;
    }
    if (b == gridDim.x - 1 && t == 0) rowstart[N] = E;
    __syncthreads();
    {
        int e = e0 + t;
        for (; e + 1536 < e1; e += 2048) {
            int p0 = pairBuf[e], p1 = pairBuf[e + 512];
            int p2 = pairBuf[e + 1024], p3 = pairBuf[e + 1536];
            int q0 = atomicAdd(&curs[p0 >> 18], 1); csr[q0] = p0 & 0x3FFFF;
            int q1 = atomicAdd(&curs[p1 >> 18], 1); csr[q1] = p1 & 0x3FFFF;
            int q2 = atomicAdd(&curs[p2 >> 18], 1); csr[q2] = p2 & 0x3FFFF;
            int q3 = atomicAdd(&curs[p3 >> 18], 1); csr[q3] = p3 & 0x3FFFF;
        }
        for (; e < e1; e += 512) {
            int pk = pairBuf[e];
            int pos = atomicAdd(&curs[pk >> 18], 1);
            csr[pos] = pk & 0x3FFFF;
        }
    }
    // pre-scale this bucket's xb rows by dinv: xs[i] = dinv[i] * x[i]  (batched 2-deep)
    {
        uint4* xb4 = (uint4*)(xb + (size_t)n0 * 32);
        int tot = nn * 8;   // 8 uint4 per row
        for (int j = t; j < tot; j += 1024) {
            int j2 = j + 512;
            uint4 u = xb4[j];
            uint4 u2;
            bool two = (j2 < tot);
            if (two) u2 = xb4[j2];
            float dv = sdv[j >> 3];
            u.x = pack_bf16(dv * bf_lo(u.x), dv * bf_hi(u.x));
            u.y = pack_bf16(dv * bf_lo(u.y), dv * bf_hi(u.y));
            u.z = pack_bf16(dv * bf_lo(u.z), dv * bf_hi(u.z));
            u.w = pack_bf16(dv * bf_lo(u.w), dv * bf_hi(u.w));
            xb4[j] = u;
            if (two) {
                float dv2 = sdv[j2 >> 3];
                u2.x = pack_bf16(dv2 * bf_lo(u2.x), dv2 * bf_hi(u2.x));
                u2.y = pack_bf16(dv2 * bf_lo(u2.y), dv2 * bf_hi(u2.y));
                u2.z = pack_bf16(dv2 * bf_lo(u2.z), dv2 * bf_hi(u2.z));
                u2.w = pack_bf16(dv2 * bf_lo(u2.w), dv2 * bf_hi(u2.w));
                xb4[j2] = u2;
            }
        }
    }
}

// ------- fused gather1+layer1+layer2, LDS phase-overlay: 34816 B -> 4 blocks/CU = 32 waves/CU -------
// R8 at 44KB LDS gave 3 blk/CU, measured occupancy 56.7%, gather 3.0 TB/s (18% under ceiling).
// sA(9KB)+sB/W1T(18KB) are dead after MFMA1; sC(17KB)+W2T(17KB) overlay them after the barrier.
// Max live = 34816 B -> 4 blk/CU; more resident blocks fill barrier-tail bubbles with gather waves.
// smem layout (uints): phase A: uA[0..2304) gather-out, uB1[2304..6912) W1T(stride 36)
//                      phase B: uC[0..4352) h1(stride 68), uB2[4352..8704) W2T(stride 68)
//                      phase C: out-stage [0..2304) (stride 36)
__global__ __launch_bounds__(512, 8) void k_gl12(const int* __restrict__ rowstart,
                                                 const int* __restrict__ csr,
                                                 const float* __restrict__ dinv,
                                                 const uint4* __restrict__ xb4,
                                                 const unsigned int* __restrict__ w1p,
                                                 const float* __restrict__ b1,
                                                 const unsigned int* __restrict__ w2p,
                                                 unsigned int* __restrict__ xs2b, int N) {
    __shared__ unsigned int smem[8704];   // 34816 B
    unsigned int* uA  = smem;             // gather out, stride 36
    unsigned int* uB1 = smem + 2304;      // W1T, stride 36
    unsigned int* uC  = smem;             // h1, stride 68 (phase B)
    unsigned int* uB2 = smem + 4352;      // W2T, stride 68 (phase B)
    const int t = threadIdx.x;
    const int w = t >> 6;        // 0..7
    const int wr = w & 3;        // MFMA row group
    const int wn = w >> 2;       // MFMA col half
    const int l = t & 63;
    const int half = l >> 5;
    const int h = l & 31;
    const int sub = h >> 3;
    const int c = h & 7;
    const int hb = half * 32;
    const int n16 = l & 15;
    const int quad = l >> 4;
    const int row0 = blockIdx.x * 64;

    // stage W1T early: L2-hot loads overlap the random gather below
    {
        const uint4* w1p4 = (const uint4*)w1p;
        for (int j = t; j < 1024; j += 512) {
            int n = j >> 3, kp4 = j & 7;
            *(uint4*)&uB1[n * 36 + kp4 * 4] = w1p4[j];
        }
    }

    // gather phase: wave w -> rows [w*8, w*8+8); each 32-lane half does 4 nodes (depth-4 pipeline)
    for (int it = 0; it < 4; ++it) {
        const int r = w * 8 + it * 2 + half;
        const int node = row0 + r;
        float acc[8] = {0.f, 0.f, 0.f, 0.f, 0.f, 0.f, 0.f, 0.f};
        uint4 us = make_uint4(0u, 0u, 0u, 0u);
        float dd = 0.f;
        if (node < N) {
            const int rs = rowstart[node];
            const int re = rowstart[node + 1];
            us = xb4[(size_t)node * 8 + c];
            dd = dinv[node];
            for (int base = rs; base < re; base += 32) {
                int idx = base + h;
                int sE = (idx < re) ? csr[idx] : 0;
                int cnt = re - base; if (cnt > 32) cnt = 32;
                int groups = (cnt + 3) >> 2;   // <= 8
                uint4 u0, u1, u2, u3;
                {
                    int sk;
                    if (0 < groups) { sk = __shfl(sE, hb + 0 + sub);  u0 = xb4[(size_t)sk * 8 + c]; }
                    if (1 < groups) { sk = __shfl(sE, hb + 4 + sub);  u1 = xb4[(size_t)sk * 8 + c]; }
                    if (2 < groups) { sk = __shfl(sE, hb + 8 + sub);  u2 = xb4[(size_t)sk * 8 + c]; }
                    if (3 < groups) { sk = __shfl(sE, hb + 12 + sub); u3 = xb4[(size_t)sk * 8 + c]; }
                }
                for (int g = 0; g < groups; g += 4) {
                    uint4 c0 = u0, c1 = u1, c2 = u2, c3 = u3;
                    {   // prefetch quad g+4..g+7
                        int sk;
                        if (g + 4 < groups) { sk = __shfl(sE, hb + (g + 4) * 4 + sub); u0 = xb4[(size_t)sk * 8 + c]; }
                        if (g + 5 < groups) { sk = __shfl(sE, hb + (g + 5) * 4 + sub); u1 = xb4[(size_t)sk * 8 + c]; }
                        if (g + 6 < groups) { sk = __shfl(sE, hb + (g + 6) * 4 + sub); u2 = xb4[(size_t)sk * 8 + c]; }
                        if (g + 7 < groups) { sk = __shfl(sE, hb + (g + 7) * 4 + sub); u3 = xb4[(size_t)sk * 8 + c]; }
                    }
                    if ((g + 0) * 4 + sub < cnt) ACC8(c0);
                    if ((g + 1) * 4 + sub < cnt) ACC8(c1);
                    if ((g + 2) * 4 + sub < cnt) ACC8(c2);
                    if ((g + 3) * 4 + sub < cnt) ACC8(c3);
                }
            }
        }
        #pragma unroll
        for (int m = 8; m < 32; m <<= 1)
            #pragma unroll
            for (int i = 0; i < 8; ++i) acc[i] += __shfl_xor(acc[i], m);
        if (sub == 0) {
            uint4 o;
            if (node < N) {
                o.x = pack_bf16(dd * (acc[0] + bf_lo(us.x)), dd * (acc[1] + bf_hi(us.x)));
                o.y = pack_bf16(dd * (acc[2] + bf_lo(us.y)), dd * (acc[3] + bf_hi(us.y)));
                o.z = pack_bf16(dd * (acc[4] + bf_lo(us.z)), dd * (acc[5] + bf_hi(us.z)));
                o.w = pack_bf16(dd * (acc[6] + bf_lo(us.w)), dd * (acc[7] + bf_hi(us.w)));
            } else {
                o = make_uint4(0u, 0u, 0u, 0u);
            }
            *(uint4*)&uA[r * 36 + c * 4] = o;
        }
    }
    __syncthreads();

    // ---- layer 1 MFMA: wave handles rows wr*16..+16, nt = wn*4 .. wn*4+3 ----
    f32x4 acc1[4];
    #pragma unroll
    for (int k = 0; k < 4; ++k) acc1[k] = (f32x4){0.f, 0.f, 0.f, 0.f};
    {
        const int am = wr * 16 + n16;
        bf8_t a0 = *(const bf8_t*)&uA[am * 36 + quad * 4];
        bf8_t a1 = *(const bf8_t*)&uA[am * 36 + 16 + quad * 4];
        #pragma unroll
        for (int k = 0; k < 4; ++k) {
            int nt = wn * 4 + k;
            bf8_t b0 = *(const bf8_t*)&uB1[(nt * 16 + n16) * 36 + quad * 4];
            bf8_t b1v = *(const bf8_t*)&uB1[(nt * 16 + n16) * 36 + 16 + quad * 4];
            acc1[k] = __builtin_amdgcn_mfma_f32_16x16x32_bf16(a0, b0, acc1[k], 0, 0, 0);
            acc1[k] = __builtin_amdgcn_mfma_f32_16x16x32_bf16(a1, b1v, acc1[k], 0, 0, 0);
        }
    }
    __syncthreads();   // uA/uB1 dead; uC/uB2 overlay them

    // h1 = relu(acc1 + b1) -> uC (bf16, stride 136); stage W2T -> uB2 (stride 68)
    {
        unsigned short* sC16 = (unsigned short*)uC;
        #pragma unroll
        for (int k = 0; k < 4; ++k) {
            int col = (wn * 4 + k) * 16 + n16;
            float bv = b1[col];
            #pragma unroll
            for (int reg = 0; reg < 4; ++reg) {
                int r = wr * 16 + quad * 4 + reg;
                sC16[r * 136 + col] = bf16_1(fmaxf(acc1[k][reg] + bv, 0.f));
            }
        }
    }
    {
        const uint4* w2p4 = (const uint4*)w2p;
        for (int j = t; j < 1024; j += 512) {
            int n = j >> 4, kp4 = j & 15;
            *(uint4*)&uB2[n * 68 + kp4 * 4] = w2p4[j];
        }
    }
    __syncthreads();

    // ---- layer 2 MFMA: rows wr*16, nt = wn*2 + {0,1} ----
    f32x4 acc2[2];
    #pragma unroll
    for (int k = 0; k < 2; ++k) acc2[k] = (f32x4){0.f, 0.f, 0.f, 0.f};
    {
        const int am = wr * 16 + n16;
        #pragma unroll
        for (int ks = 0; ks < 4; ++ks) {
            bf8_t a = *(const bf8_t*)&uC[am * 68 + ks * 16 + quad * 4];
            #pragma unroll
            for (int k = 0; k < 2; ++k) {
                int nt = wn * 2 + k;
                bf8_t b = *(const bf8_t*)&uB2[(nt * 16 + n16) * 68 + ks * 16 + quad * 4];
                acc2[k] = __builtin_amdgcn_mfma_f32_16x16x32_bf16(a, b, acc2[k], 0, 0, 0);
            }
        }
    }
    __syncthreads();   // uC/uB2 dead; out-stage overlays at offset 0

    {
        unsigned short* sA16 = (unsigned short*)smem;
        #pragma unroll
        for (int reg = 0; reg < 4; ++reg) {
            int r = wr * 16 + quad * 4 + reg;
            int row = row0 + r;
            float dd2 = (row < N) ? dinv[row] : 0.f;
            #pragma unroll
            for (int k = 0; k < 2; ++k) {
                int nt = wn * 2 + k;
                sA16[r * 72 + nt * 16 + n16] = bf16_1(acc2[k][reg] * dd2);
            }
        }
    }
    __syncthreads();
    {
        int i = t;   // exactly 512 uint4 outputs, one per thread
        int r = i >> 3, cc = i & 7;
        int row = row0 + r;
        if (row < N)
            ((uint4*)xs2b)[(size_t)row * 8 + cc] = *(uint4*)&smem[r * 36 + cc * 4];
    }
}

// ------- gather_pairs: cB[b] = [h2(u), h2(i)]; one pair/wave, DEPTH-4 pipeline -------
__global__ __launch_bounds__(256) void k_gather_pairs(const int* __restrict__ rowstart,
                                                      const int* __restrict__ csr,
                                                      const float* __restrict__ dinv,
                                                      const uint4* __restrict__ xs2b4,
                                                      const float* __restrict__ b2,
                                                      const int* __restrict__ ui,
                                                      const int* __restrict__ ii,
                                                      float* __restrict__ cB, int B) {
    const int w = threadIdx.x >> 6;
    const int b = blockIdx.x * 4 + w;
    const int l = threadIdx.x & 63;
    const int half = l >> 5;
    const int h = l & 31;
    const int sub = h >> 3;
    const int c = h & 7;
    const int hb = half * 32;
    if (b >= B) return;
    const int node = (half == 0) ? (ui[b] - 1) : (N_USERS_C + ii[b] - 1);
    const int rs = rowstart[node];
    const int re = rowstart[node + 1];
    uint4 us = xs2b4[(size_t)node * 8 + c];   // self term early
    float dd = dinv[node];

    float acc[8] = {0.f, 0.f, 0.f, 0.f, 0.f, 0.f, 0.f, 0.f};
    for (int base = rs; base < re; base += 32) {
        int idx = base + h;
        int sE = (idx < re) ? csr[idx] : 0;
        int cnt = re - base; if (cnt > 32) cnt = 32;
        int groups = (cnt + 3) >> 2;
        uint4 u0, u1, u2, u3;
        {
            int sk;
            if (0 < groups) { sk = __shfl(sE, hb + 0 + sub);  u0 = xs2b4[(size_t)sk * 8 + c]; }
            if (1 < groups) { sk = __shfl(sE, hb + 4 + sub);  u1 = xs2b4[(size_t)sk * 8 + c]; }
            if (2 < groups) { sk = __shfl(sE, hb + 8 + sub);  u2 = xs2b4[(size_t)sk * 8 + c]; }
            if (3 < groups) { sk = __shfl(sE, hb + 12 + sub); u3 = xs2b4[(size_t)sk * 8 + c]; }
        }
        for (int g = 0; g < groups; g += 4) {
            uint4 c0 = u0, c1 = u1, c2 = u2, c3 = u3;
            {
                int sk;
                if (g + 4 < groups) { sk = __shfl(sE, hb + (g + 4) * 4 + sub); u0 = xs2b4[(size_t)sk * 8 + c]; }
                if (g + 5 < groups) { sk = __shfl(sE, hb + (g + 5) * 4 + sub); u1 = xs2b4[(size_t)sk * 8 + c]; }
                if (g + 6 < groups) { sk = __shfl(sE, hb + (g + 6) * 4 + sub); u2 = xs2b4[(size_t)sk * 8 + c]; }
                if (g + 7 < groups) { sk = __shfl(sE, hb + (g + 7) * 4 + sub); u3 = xs2b4[(size_t)sk * 8 + c]; }
            }
            if ((g + 0) * 4 + sub < cnt) ACC8(c0);
            if ((g + 1) * 4 + sub < cnt) ACC8(c1);
            if ((g + 2) * 4 + sub < cnt) ACC8(c2);
            if ((g + 3) * 4 + sub < cnt) ACC8(c3);
        }
    }
    #pragma unroll
    for (int m = 8; m < 32; m <<= 1)
        #pragma unroll
        for (int i = 0; i < 8; ++i) acc[i] += __shfl_xor(acc[i], m);
    if (sub == 0) {
        float4 s0, s1;
        s0.x = bf_lo(us.x); s0.y = bf_hi(us.x); s0.z = bf_lo(us.y); s0.w = bf_hi(us.y);
        s1.x = bf_lo(us.z); s1.y = bf_hi(us.z); s1.z = bf_lo(us.w); s1.w = bf_hi(us.w);
        float4 bb0 = ((const float4*)b2)[c * 2];
        float4 bb1 = ((const float4*)b2)[c * 2 + 1];
        float4 o0, o1;
        o0.x = dd * (acc[0] + s0.x) + bb0.x;
        o0.y = dd * (acc[1] + s0.y) + bb0.y;
        o0.z = dd * (acc[2] + s0.z) + bb0.z;
        o0.w = dd * (acc[3] + s0.w) + bb0.w;
        o1.x = dd * (acc[4] + s1.x) + bb1.x;
        o1.y = dd * (acc[5] + s1.y) + bb1.y;
        o1.z = dd * (acc[6] + s1.z) + bb1.z;
        o1.w = dd * (acc[7] + s1.w) + bb1.w;
        ((float4*)cB)[(size_t)b * 32 + half * 16 + c * 2] = o0;
        ((float4*)cB)[(size_t)b * 32 + half * 16 + c * 2 + 1] = o1;
    }
}

// ---------------- fused MLP: 32 rows/block ----------------
__global__ __launch_bounds__(256) void k_mlp(const float* __restrict__ cB,
                                             const float* __restrict__ fcW1, const float* __restrict__ fcb1,
                                             const float* __restrict__ g1,   const float* __restrict__ be1,
                                             const float* __restrict__ fcW2, const float* __restrict__ fcb2,
                                             const float* __restrict__ g2,   const float* __restrict__ be2,
                                             const float* __restrict__ fcW3, const float* __restrict__ fcb3,
                                             float* __restrict__ out) {
    __shared__ float sIn[32 * 128];
    __shared__ float sW[64 * 128];
    const int t = threadIdx.x;
    const int row0 = blockIdx.x * 32;
    const int rg = t >> 4;
    const int cg = t & 15;

    for (int i = t; i < 1024; i += 256) {
        int r = i >> 5, c4 = i & 31;
        *(float4*)&sIn[r * 128 + c4 * 4] = *(const float4*)&cB[(size_t)(row0 + r) * 128 + c4 * 4];
    }

    float acc1[2][8];
    {
        float4 b01 = *(const float4*)&fcb1[cg * 8];
        float4 b23 = *(const float4*)&fcb1[cg * 8 + 4];
        #pragma unroll
        for (int jj = 0; jj < 2; ++jj) {
            acc1[jj][0] = b01.x; acc1[jj][1] = b01.y; acc1[jj][2] = b01.z; acc1[jj][3] = b01.w;
            acc1[jj][4] = b23.x; acc1[jj][5] = b23.y; acc1[jj][6] = b23.z; acc1[jj][7] = b23.w;
        }
    }
    for (int s = 0; s < 2; ++s) {
        __syncthreads();
        for (int i = t; i < 2048; i += 256) {
            int k = i >> 5, c4 = i & 31;
            *(float4*)&sW[k * 128 + c4 * 4] = *(const float4*)&fcW1[(size_t)(64 * s + k) * 128 + c4 * 4];
        }
        __syncthreads();
        for (int k0 = 0; k0 < 64; k0 += 4) {
            float4 a[2];
            #pragma unroll
            for (int jj = 0; jj < 2; ++jj)
                a[jj] = *(const float4*)&sIn[(rg * 2 + jj) * 128 + 64 * s + k0];
            #pragma unroll
            for (int kk = 0; kk < 4; ++kk) {
                float4 w0 = *(const float4*)&sW[(k0 + kk) * 128 + cg * 8];
                float4 w1 = *(const float4*)&sW[(k0 + kk) * 128 + cg * 8 + 4];
                #pragma unroll
                for (int jj = 0; jj < 2; ++jj) {
                    float f = ((const float*)&a[jj])[kk];
                    acc1[jj][0] += f * w0.x; acc1[jj][1] += f * w0.y;
                    acc1[jj][2] += f * w0.z; acc1[jj][3] += f * w0.w;
                    acc1[jj][4] += f * w1.x; acc1[jj][5] += f * w1.y;
                    acc1[jj][6] += f * w1.z; acc1[jj][7] += f * w1.w;
                }
            }
        }
    }
    __syncthreads();

    {
        float4 g01 = *(const float4*)&g1[cg * 8];
        float4 g23 = *(const float4*)&g1[cg * 8 + 4];
        float4 e01 = *(const float4*)&be1[cg * 8];
        float4 e23 = *(const float4*)&be1[cg * 8 + 4];
        float gv[8] = {g01.x, g01.y, g01.z, g01.w, g23.x, g23.y, g23.z, g23.w};
        float ev[8] = {e01.x, e01.y, e01.z, e01.w, e23.x, e23.y, e23.z, e23.w};
        #pragma unroll
        for (int jj = 0; jj < 2; ++jj) {
            float s_ = 0.f, ss = 0.f;
            #pragma unroll
            for (int c = 0; c < 8; ++c) { float v = acc1[jj][c]; s_ += v; ss += v * v; }
            #pragma unroll
            for (int m = 1; m < 16; m <<= 1) { s_ += __shfl_xor(s_, m); ss += __shfl_xor(ss, m); }
            float mu = s_ * (1.0f / 128.0f);
            float var = ss * (1.0f / 128.0f) - mu * mu;
            float rs = rsqrtf(var + 1e-5f);
            #pragma unroll
            for (int c = 0; c < 8; ++c) {
                float z = (acc1[jj][c] - mu) * rs * gv[c] + ev[c];
                sIn[(rg * 2 + jj) * 128 + cg * 8 + c] = fmaxf(z, 0.f);
            }
        }
    }
    __syncthreads();

    for (int i = t; i < 2048; i += 256) {
        int k = i >> 4, c4 = i & 15;
        *(float4*)&sW[k * 64 + c4 * 4] = *(const float4*)&fcW2[(size_t)k * 64 + c4 * 4];
    }
    float acc2[2][4];
    {
        float4 bv = *(const float4*)&fcb2[cg * 4];
        #pragma unroll
        for (int jj = 0; jj < 2; ++jj) {
            acc2[jj][0] = bv.x; acc2[jj][1] = bv.y; acc2[jj][2] = bv.z; acc2[jj][3] = bv.w;
        }
    }
    __syncthreads();
    for (int k0 = 0; k0 < 128; k0 += 4) {
        float4 a[2], w[4];
        #pragma unroll
        for (int jj = 0; jj < 2; ++jj) a[jj] = *(const float4*)&sIn[(rg * 2 + jj) * 128 + k0];
        #pragma unroll
        for (int kk = 0; kk < 4; ++kk) w[kk] = *(const float4*)&sW[(k0 + kk) * 64 + cg * 4];
        #pragma unroll
        for (int jj = 0; jj < 2; ++jj) {
            const float* aj = (const float*)&a[jj];
            #pragma unroll
            for (int kk = 0; kk < 4; ++kk) {
                float f = aj[kk];
                acc2[jj][0] += f * w[kk].x; acc2[jj][1] += f * w[kk].y;
                acc2[jj][2] += f * w[kk].z; acc2[jj][3] += f * w[kk].w;
            }
        }
    }

    {
        float4 gv4 = *(const float4*)&g2[cg * 4];
        float4 ev4 = *(const float4*)&be2[cg * 4];
        float4 w34 = *(const float4*)&fcW3[cg * 4];
        float gv[4] = {gv4.x, gv4.y, gv4.z, gv4.w};
        float ev[4] = {ev4.x, ev4.y, ev4.z, ev4.w};
        float wv[4] = {w34.x, w34.y, w34.z, w34.w};
        float b3 = fcb3[0];
        #pragma unroll
        for (int jj = 0; jj < 2; ++jj) {
            float s_ = 0.f, ss = 0.f;
            #pragma unroll
            for (int c = 0; c < 4; ++c) { float v = acc2[jj][c]; s_ += v; ss += v * v; }
            #pragma unroll
            for (int m = 1; m < 16; m <<= 1) { s_ += __shfl_xor(s_, m); ss += __shfl_xor(ss, m); }
            float mu = s_ * (1.0f / 64.0f);
            float var = ss * (1.0f / 64.0f) - mu * mu;
            float rs = rsqrtf(var + 1e-5f);
            float p = 0.f;
            #pragma unroll
            for (int c = 0; c < 4; ++c) {
                float z = fmaxf((acc2[jj][c] - mu) * rs * gv[c] + ev[c], 0.f);
                p += z * wv[c];
            }
            #pragma unroll
            for (int m = 1; m < 16; m <<= 1) p += __shfl_xor(p, m);
            if (cg == 0) out[row0 + rg * 2 + jj] = 1.0f / (1.0f + expf(-(p + b3)));
        }
    }
}

extern "C" void kernel_launch(void* const* d_in, const int* in_sizes, int n_in,
                              void* d_out, int out_size, void* d_ws, size_t ws_size,
                              hipStream_t stream) {
    const float* x    = (const float*)d_in[0];
    const int*   src  = (const int*)d_in[1];
    const int*   dst  = (const int*)d_in[2];
    const int*   ui   = (const int*)d_in[3];
    const int*   ii   = (const int*)d_in[4];
    const float* W1   = (const float*)d_in[5];
    const float* b1   = (const float*)d_in[6];
    const float* W2   = (const float*)d_in[7];
    const float* b2   = (const float*)d_in[8];
    const float* fcW1 = (const float*)d_in[9];
    const float* fcb1 = (const float*)d_in[10];
    const float* g1   = (const float*)d_in[11];
    const float* be1  = (const float*)d_in[12];
    const float* fcW2 = (const float*)d_in[13];
    const float* fcb2 = (const float*)d_in[14];
    const float* g2   = (const float*)d_in[15];
    const float* be2  = (const float*)d_in[16];
    const float* fcW3 = (const float*)d_in[17];
    const float* fcb3 = (const float*)d_in[18];
    float* out = (float*)d_out;

    const int N = in_sizes[0] / 64;          // 150000
    const int E = in_sizes[1];               // 2400000
    const int B = in_sizes[3];               // 16384
    const int NBK = (N + BK_NODES - 1) >> BK_SHIFT;   // 293
    const int EB2 = (E + 4095) / 4096;       // 586 (hist blocks)
    const int n2 = N * 32;
    const int XB = (n2 + 2047) / 2048;

    // ---- workspace layout (~77 MB) ----
    float* ws   = (float*)d_ws;
    float* dinv = ws;                                   // N
    int* rowstart = (int*)(dinv + N);                   // N+1
    int* csr      = rowstart + (N + 1);                 // E
    unsigned int* xb = (unsigned int*)(csr + E);        // N*32 (bf16 x, pre-scaled by dinv after bscatter)
    unsigned int* bufU = xb + (size_t)N * 32;           // N*32: CSR scratch
    unsigned int* xs2b = bufU + (size_t)N * 32;         // N*32 (bf16 xs2)
    float* cB = (float*)(xs2b + (size_t)N * 32);        // B*128 f32
    unsigned int* w1p = (unsigned int*)(cB + (size_t)B * 128);  // 4096 (packed W1T) - outside bufU!
    unsigned int* w2p = w1p + 4096;                     // 4096 (packed W2T)
    int* pairBuf = (int*)bufU;                          // E
    int* chist   = pairBuf + E;                         // 512*CPAD (line-padded)
    int* bcursor = chist + 512 * CPAD;                  // 512*CPAD (adjacent: one memset)

    // ---- CSR build + bf16 conversion + weight pre-pack ----
    hipMemsetAsync(chist, 0, 2 * 512 * CPAD * sizeof(int), stream);   // chist + bcursor
    k_pre<<<EB2 + XB + 2, 512, 0, stream>>>(dst, chist, x, xb, W1, W2, w1p, w2p,
                                            E, NBK, EB2, n2, XB);
    k_bin<<<EB2, 512, 0, stream>>>(src, dst, chist, bcursor, pairBuf, E, NBK);
    k_bscatter<<<NBK, 512, 0, stream>>>(pairBuf, chist, rowstart, dinv, csr, xb, N, E, NBK);

    // ---- fused gather1 + layer1 + layer2 (512 thr, 34.8KB LDS -> 4 blk/CU = 32 waves/CU) ----
    k_gl12<<<(N + 63) / 64, 512, 0, stream>>>(rowstart, csr, dinv, (const uint4*)xb,
                                              w1p, b1, w2p, xs2b, N);

    // ---- pruned gather2 + concat (1 pair per wave, depth-4 pipeline) ----
    k_gather_pairs<<<(B + 3) / 4, 256, 0, stream>>>(rowstart, csr, dinv, (const uint4*)xs2b,
                                                    b2, ui, ii, cB, B);

    // ---- fused MLP ----
    k_mlp<<<B / 32, 256, 0, stream>>>(cB, fcW1, fcb1, g1, be1,
                                      fcW2, fcb2, g2, be2, fcW3, fcb3, out);
}

// Round 10
// 325.533 us; speedup vs baseline: 1.0758x; 1.0758x over previous
//
#include <hip/hip_runtime.h>
#include <hip/hip_bf16.h>
#include <math.h>

#define N_USERS_C 100000
#define BK_SHIFT 9
#define BK_NODES 512
// hot global atomic counters padded to one per 64B L2 line (16 ints)
#define CPAD 16

typedef __bf16 bf8_t __attribute__((ext_vector_type(8)));
typedef float f32x4 __attribute__((ext_vector_type(4)));

__device__ __forceinline__ unsigned int pack_bf16(float a, float b) {
    __hip_bfloat16 ha = __float2bfloat16(a), hb = __float2bfloat16(b);
    return ((unsigned int)(*(unsigned short*)&hb) << 16) | (unsigned int)(*(unsigned short*)&ha);
}
__device__ __forceinline__ unsigned short bf16_1(float a) {
    __hip_bfloat16 ha = __float2bfloat16(a);
    return *(unsigned short*)&ha;
}
__device__ __forceinline__ float bf_lo(unsigned int u) { return __uint_as_float(u << 16); }
__device__ __forceinline__ float bf_hi(unsigned int u) { return __uint_as_float(u & 0xffff0000u); }

#define ACC8(uu) { acc[0] += bf_lo(uu.x); acc[1] += bf_hi(uu.x); \
                   acc[2] += bf_lo(uu.y); acc[3] += bf_hi(uu.y); \
                   acc[4] += bf_lo(uu.z); acc[5] += bf_hi(uu.z); \
                   acc[6] += bf_lo(uu.w); acc[7] += bf_hi(uu.w); }

// ------- merged: bucket histogram (4096 edges/blk) || x->bf16 || W1/W2 bf16-pair pack -------
__global__ __launch_bounds__(512) void k_pre(const int* __restrict__ dst, int* __restrict__ chist,
                                             const float* __restrict__ x, unsigned int* __restrict__ xb,
                                             const float* __restrict__ W1, const float* __restrict__ W2,
                                             unsigned int* __restrict__ w1p, unsigned int* __restrict__ w2p,
                                             int E, int nbk, int EB2, int n2, int XB) {
    __shared__ int lcnt[BK_NODES];
    const int bid = blockIdx.x;
    const int t = threadIdx.x;
    if (bid < EB2) {
        if (t < nbk) lcnt[t] = 0;
        __syncthreads();
        int e0 = bid * 4096;
        #pragma unroll
        for (int j = 0; j < 8; ++j) {
            int e = e0 + j * 512 + t;
            if (e < E) atomicAdd(&lcnt[dst[e] >> BK_SHIFT], 1);
        }
        __syncthreads();
        if (t < nbk && lcnt[t]) atomicAdd(&chist[t * CPAD], lcnt[t]);
    } else if (bid < EB2 + XB) {
        int base = (bid - EB2) * 2048;
        #pragma unroll
        for (int j = 0; j < 4; ++j) {
            int i = base + j * 512 + t;
            if (i < n2) {
                float2 v = ((const float2*)x)[i];
                xb[i] = pack_bf16(v.x, v.y);
            }
        }
    } else if (bid == EB2 + XB) {
        // pack W1^T: w1p[n*32+kp] = bf16(W1[2kp][n]) | bf16(W1[2kp+1][n])<<16 ; n<128, kp<32
        #pragma unroll
        for (int j = 0; j < 8; ++j) {
            int i = j * 512 + t;
            int kp = i >> 7, n = i & 127;
            w1p[n * 32 + kp] = pack_bf16(W1[(size_t)(2 * kp) * 128 + n],
                                         W1[(size_t)(2 * kp + 1) * 128 + n]);
        }
    } else {
        // pack W2^T: w2p[n*64+kp] ; n<64, kp<64
        #pragma unroll
        for (int j = 0; j < 8; ++j) {
            int i = j * 512 + t;
            int kp = i >> 6, n = i & 63;
            w2p[n * 64 + kp] = pack_bf16(W2[(size_t)(2 * kp) * 64 + n],
                                         W2[(size_t)(2 * kp + 1) * 64 + n]);
        }
    }
}

// ---------------- pass 1: counting sort, 4096 edges/block, local chist scan ----------------
__global__ __launch_bounds__(512) void k_bin(const int* __restrict__ src,
                                             const int* __restrict__ dst,
                                             const int* __restrict__ chist,
                                             int* __restrict__ bcursor0,
                                             int* __restrict__ pairBuf, int E, int nbk) {
    __shared__ int lcnt[BK_NODES];
    __shared__ int lofs[BK_NODES];
    __shared__ int delta[BK_NODES];
    __shared__ int waveSum[8];
    __shared__ int sPack[4096];
    __shared__ unsigned short sBkt[4096];
    const int t = threadIdx.x;
    const int lane = t & 63;
    const int w = t >> 6;
    const int e0 = blockIdx.x * 4096;
    if (t < nbk) lcnt[t] = 0;
    __syncthreads();

    int mySrc[8], myB[8], myDl[8];
    #pragma unroll
    for (int j = 0; j < 8; ++j) {
        int e = e0 + j * 512 + t;
        if (e < E) {
            int sv = src[e], dv = dst[e];
            mySrc[j] = sv; myB[j] = dv >> BK_SHIFT; myDl[j] = dv & (BK_NODES - 1);
            atomicAdd(&lcnt[myB[j]], 1);
        } else myB[j] = -1;
    }
    __syncthreads();

    // wave-shuffle exclusive scan over lcnt, and local scan of chist for base
    int v = (t < nbk) ? lcnt[t] : 0;
    int inc = v;
    #pragma unroll
    for (int off = 1; off < 64; off <<= 1) {
        int n = __shfl_up(inc, off);
        if (lane >= off) inc += n;
    }
    if (lane == 63) waveSum[w] = inc;
    int cv = (t < nbk) ? chist[t * CPAD] : 0;   // global bucket count (padded)
    int cinc = cv;
    #pragma unroll
    for (int off = 1; off < 64; off <<= 1) {
        int n = __shfl_up(cinc, off);
        if (lane >= off) cinc += n;
    }
    __shared__ int cWaveSum[8];
    if (lane == 63) cWaveSum[w] = cinc;
    __syncthreads();
    int wp = 0, cwp = 0;
    #pragma unroll
    for (int i = 0; i < 8; ++i) {
        wp += (i < w) ? waveSum[i] : 0;
        cwp += (i < w) ? cWaveSum[i] : 0;
    }
    int ex = wp + inc - v;         // exclusive prefix of local counts
    int cbase = cwp + cinc - cv;   // global bucket base (exclusive scan of chist)
    if (t < nbk) {
        lofs[t] = ex;
        int gb = cbase + ((v > 0) ? atomicAdd(&bcursor0[t * CPAD], v) : 0);
        delta[t] = gb - ex;
    }
    __syncthreads();

    #pragma unroll
    for (int j = 0; j < 8; ++j) {
        if (myB[j] >= 0) {
            int p = atomicAdd(&lofs[myB[j]], 1);
            sPack[p] = mySrc[j] | (myDl[j] << 18);   // src < 2^18
            sBkt[p] = (unsigned short)myB[j];
        }
    }
    __syncthreads();
    int total = (E - e0 < 4096) ? (E - e0) : 4096;
    for (int i = t; i < total; i += 512)
        pairBuf[delta[sBkt[i]] + i] = sPack[i];
}

// ------- pass 2: per-bucket rowstart/dinv + csr scatter + xb pre-scale by dinv -------
// latency-critical loops batched 4-deep (293 blocks -> ~1 block/CU, nothing else hides latency)
__global__ __launch_bounds__(512) void k_bscatter(const int* __restrict__ pairBuf,
                                                  const int* __restrict__ chist,
                                                  int* __restrict__ rowstart,
                                                  float* __restrict__ dinv,
                                                  int* __restrict__ csr,
                                                  unsigned int* __restrict__ xb,
                                                  int N, int E, int nbk) {
    const int b = blockIdx.x;
    const int n0 = b << BK_SHIFT;
    int nn = N - n0; if (nn > BK_NODES) nn = BK_NODES;
    __shared__ int hist[BK_NODES];
    __shared__ int curs[BK_NODES];
    __shared__ float sdv[BK_NODES];
    __shared__ int waveSum[8];
    __shared__ int sE0, sE1;
    const int t = threadIdx.x;
    const int lane = t & 63;
    const int w = t >> 6;

    // local exclusive scan of chist -> this bucket's [e0,e1)
    {
        int cv = (t < nbk) ? chist[t * CPAD] : 0;
        int cinc = cv;
        #pragma unroll
        for (int off = 1; off < 64; off <<= 1) {
            int n = __shfl_up(cinc, off);
            if (lane >= off) cinc += n;
        }
        if (lane == 63) waveSum[w] = cinc;
        if (t < nn) hist[t] = 0;
        __syncthreads();
        int cwp = 0;
        #pragma unroll
        for (int i = 0; i < 8; ++i) cwp += (i < w) ? waveSum[i] : 0;
        if (t == b) { sE0 = cwp + cinc - cv; sE1 = cwp + cinc; }
    }
    __syncthreads();
    const int e0 = sE0, e1 = sE1;

    {
        int e = e0 + t;
        for (; e + 1536 < e1; e += 2048) {
            int p0 = pairBuf[e], p1 = pairBuf[e + 512];
            int p2 = pairBuf[e + 1024], p3 = pairBuf[e + 1536];
            atomicAdd(&hist[p0 >> 18], 1);
            atomicAdd(&hist[p1 >> 18], 1);
            atomicAdd(&hist[p2 >> 18], 1);
            atomicAdd(&hist[p3 >> 18], 1);
        }
        for (; e < e1; e += 512)
            atomicAdd(&hist[pairBuf[e] >> 18], 1);
    }
    __syncthreads();

    int v = (t < nn) ? hist[t] : 0;
    int inc = v;
    #pragma unroll
    for (int off = 1; off < 64; off <<= 1) {
        int n = __shfl_up(inc, off);
        if (lane >= off) inc += n;
    }
    if (lane == 63) waveSum[w] = inc;
    __syncthreads();
    int wp = 0;
    #pragma unroll
    for (int i = 0; i < 8; ++i) wp += (i < w) ? waveSum[i] : 0;
    int ex = wp + inc - v;
    if (t < nn) {
        int r = e0 + ex;
        rowstart[n0 + t] = r;
        curs[t] = r;
        float dv = rsqrtf((float)(v + 1));
        dinv[n0 + t] = dv;
        sdv[t] = dv;
    }
    if (b == gridDim.x - 1 && t == 0) rowstart[N] = E;
    __syncthreads();
    {
        int e = e0 + t;
        for (; e + 1536 < e1; e += 2048) {
            int p0 = pairBuf[e], p1 = pairBuf[e + 512];
            int p2 = pairBuf[e + 1024], p3 = pairBuf[e + 1536];
            int q0 = atomicAdd(&curs[p0 >> 18], 1); csr[q0] = p0 & 0x3FFFF;
            int q1 = atomicAdd(&curs[p1 >> 18], 1); csr[q1] = p1 & 0x3FFFF;
            int q2 = atomicAdd(&curs[p2 >> 18], 1); csr[q2] = p2 & 0x3FFFF;
            int q3 = atomicAdd(&curs[p3 >> 18], 1); csr[q3] = p3 & 0x3FFFF;
        }
        for (; e < e1; e += 512) {
            int pk = pairBuf[e];
            int pos = atomicAdd(&curs[pk >> 18], 1);
            csr[pos] = pk & 0x3FFFF;
        }
    }
    // pre-scale this bucket's xb rows by dinv: xs[i] = dinv[i] * x[i]  (batched 2-deep)
    {
        uint4* xb4 = (uint4*)(xb + (size_t)n0 * 32);
        int tot = nn * 8;   // 8 uint4 per row
        for (int j = t; j < tot; j += 1024) {
            int j2 = j + 512;
            uint4 u = xb4[j];
            uint4 u2;
            bool two = (j2 < tot);
            if (two) u2 = xb4[j2];
            float dv = sdv[j >> 3];
            u.x = pack_bf16(dv * bf_lo(u.x), dv * bf_hi(u.x));
            u.y = pack_bf16(dv * bf_lo(u.y), dv * bf_hi(u.y));
            u.z = pack_bf16(dv * bf_lo(u.z), dv * bf_hi(u.z));
            u.w = pack_bf16(dv * bf_lo(u.w), dv * bf_hi(u.w));
            xb4[j] = u;
            if (two) {
                float dv2 = sdv[j2 >> 3];
                u2.x = pack_bf16(dv2 * bf_lo(u2.x), dv2 * bf_hi(u2.x));
                u2.y = pack_bf16(dv2 * bf_lo(u2.y), dv2 * bf_hi(u2.y));
                u2.z = pack_bf16(dv2 * bf_lo(u2.z), dv2 * bf_hi(u2.z));
                u2.w = pack_bf16(dv2 * bf_lo(u2.w), dv2 * bf_hi(u2.w));
                xb4[j2] = u2;
            }
        }
    }
}

// ------- fused gather1+layer1+layer2, LDS phase-overlay (34816 B -> 4 blocks/CU) -------
// R9 confirmed the occupancy mechanism (57->76%, gather 3.0->3.5 TB/s) but __launch_bounds__(512,8)
// capped VGPR at 64 -> compiler chose 32 + SCRATCH SPILL (FETCH +63MB, WRITE +65MB) and lost 23us.
// Fix: bound (512,6) -> VGPR cap ~85, loop needs ~40-48 (no spill); 40<=64 still allows 8 waves/SIMD,
// and LDS 4x34816=139KB <= 160KB still allows 4 blocks/CU. Occupancy AND spill-free codegen together.
// smem layout (uints): phase A: uA[0..2304) gather-out, uB1[2304..6912) W1T(stride 36)
//                      phase B: uC[0..4352) h1(stride 68), uB2[4352..8704) W2T(stride 68)
//                      phase C: out-stage [0..2304) (stride 36)
__global__ __launch_bounds__(512, 6) void k_gl12(const int* __restrict__ rowstart,
                                                 const int* __restrict__ csr,
                                                 const float* __restrict__ dinv,
                                                 const uint4* __restrict__ xb4,
                                                 const unsigned int* __restrict__ w1p,
                                                 const float* __restrict__ b1,
                                                 const unsigned int* __restrict__ w2p,
                                                 unsigned int* __restrict__ xs2b, int N) {
    __shared__ unsigned int smem[8704];   // 34816 B
    unsigned int* uA  = smem;             // gather out, stride 36
    unsigned int* uB1 = smem + 2304;      // W1T, stride 36
    unsigned int* uC  = smem;             // h1, stride 68 (phase B)
    unsigned int* uB2 = smem + 4352;      // W2T, stride 68 (phase B)
    const int t = threadIdx.x;
    const int w = t >> 6;        // 0..7
    const int wr = w & 3;        // MFMA row group
    const int wn = w >> 2;       // MFMA col half
    const int l = t & 63;
    const int half = l >> 5;
    const int h = l & 31;
    const int sub = h >> 3;
    const int c = h & 7;
    const int hb = half * 32;
    const int n16 = l & 15;
    const int quad = l >> 4;
    const int row0 = blockIdx.x * 64;

    // stage W1T early: L2-hot loads overlap the random gather below
    {
        const uint4* w1p4 = (const uint4*)w1p;
        for (int j = t; j < 1024; j += 512) {
            int n = j >> 3, kp4 = j & 7;
            *(uint4*)&uB1[n * 36 + kp4 * 4] = w1p4[j];
        }
    }

    // gather phase: wave w -> rows [w*8, w*8+8); each 32-lane half does 4 nodes (depth-4 pipeline)
    for (int it = 0; it < 4; ++it) {
        const int r = w * 8 + it * 2 + half;
        const int node = row0 + r;
        float acc[8] = {0.f, 0.f, 0.f, 0.f, 0.f, 0.f, 0.f, 0.f};
        uint4 us = make_uint4(0u, 0u, 0u, 0u);
        float dd = 0.f;
        if (node < N) {
            const int rs = rowstart[node];
            const int re = rowstart[node + 1];
            us = xb4[(size_t)node * 8 + c];
            dd = dinv[node];
            for (int base = rs; base < re; base += 32) {
                int idx = base + h;
                int sE = (idx < re) ? csr[idx] : 0;
                int cnt = re - base; if (cnt > 32) cnt = 32;
                int groups = (cnt + 3) >> 2;   // <= 8
                uint4 u0, u1, u2, u3;
                {
                    int sk;
                    if (0 < groups) { sk = __shfl(sE, hb + 0 + sub);  u0 = xb4[(size_t)sk * 8 + c]; }
                    if (1 < groups) { sk = __shfl(sE, hb + 4 + sub);  u1 = xb4[(size_t)sk * 8 + c]; }
                    if (2 < groups) { sk = __shfl(sE, hb + 8 + sub);  u2 = xb4[(size_t)sk * 8 + c]; }
                    if (3 < groups) { sk = __shfl(sE, hb + 12 + sub); u3 = xb4[(size_t)sk * 8 + c]; }
                }
                for (int g = 0; g < groups; g += 4) {
                    uint4 c0 = u0, c1 = u1, c2 = u2, c3 = u3;
                    {   // prefetch quad g+4..g+7
                        int sk;
                        if (g + 4 < groups) { sk = __shfl(sE, hb + (g + 4) * 4 + sub); u0 = xb4[(size_t)sk * 8 + c]; }
                        if (g + 5 < groups) { sk = __shfl(sE, hb + (g + 5) * 4 + sub); u1 = xb4[(size_t)sk * 8 + c]; }
                        if (g + 6 < groups) { sk = __shfl(sE, hb + (g + 6) * 4 + sub); u2 = xb4[(size_t)sk * 8 + c]; }
                        if (g + 7 < groups) { sk = __shfl(sE, hb + (g + 7) * 4 + sub); u3 = xb4[(size_t)sk * 8 + c]; }
                    }
                    if ((g + 0) * 4 + sub < cnt) ACC8(c0);
                    if ((g + 1) * 4 + sub < cnt) ACC8(c1);
                    if ((g + 2) * 4 + sub < cnt) ACC8(c2);
                    if ((g + 3) * 4 + sub < cnt) ACC8(c3);
                }
            }
        }
        #pragma unroll
        for (int m = 8; m < 32; m <<= 1)
            #pragma unroll
            for (int i = 0; i < 8; ++i) acc[i] += __shfl_xor(acc[i], m);
        if (sub == 0) {
            uint4 o;
            if (node < N) {
                o.x = pack_bf16(dd * (acc[0] + bf_lo(us.x)), dd * (acc[1] + bf_hi(us.x)));
                o.y = pack_bf16(dd * (acc[2] + bf_lo(us.y)), dd * (acc[3] + bf_hi(us.y)));
                o.z = pack_bf16(dd * (acc[4] + bf_lo(us.z)), dd * (acc[5] + bf_hi(us.z)));
                o.w = pack_bf16(dd * (acc[6] + bf_lo(us.w)), dd * (acc[7] + bf_hi(us.w)));
            } else {
                o = make_uint4(0u, 0u, 0u, 0u);
            }
            *(uint4*)&uA[r * 36 + c * 4] = o;
        }
    }
    __syncthreads();

    // ---- layer 1 MFMA: wave handles rows wr*16..+16, nt = wn*4 .. wn*4+3 ----
    f32x4 acc1[4];
    #pragma unroll
    for (int k = 0; k < 4; ++k) acc1[k] = (f32x4){0.f, 0.f, 0.f, 0.f};
    {
        const int am = wr * 16 + n16;
        bf8_t a0 = *(const bf8_t*)&uA[am * 36 + quad * 4];
        bf8_t a1 = *(const bf8_t*)&uA[am * 36 + 16 + quad * 4];
        #pragma unroll
        for (int k = 0; k < 4; ++k) {
            int nt = wn * 4 + k;
            bf8_t b0 = *(const bf8_t*)&uB1[(nt * 16 + n16) * 36 + quad * 4];
            bf8_t b1v = *(const bf8_t*)&uB1[(nt * 16 + n16) * 36 + 16 + quad * 4];
            acc1[k] = __builtin_amdgcn_mfma_f32_16x16x32_bf16(a0, b0, acc1[k], 0, 0, 0);
            acc1[k] = __builtin_amdgcn_mfma_f32_16x16x32_bf16(a1, b1v, acc1[k], 0, 0, 0);
        }
    }
    __syncthreads();   // uA/uB1 dead; uC/uB2 overlay them

    // h1 = relu(acc1 + b1) -> uC (bf16, stride 136); stage W2T -> uB2 (stride 68)
    {
        unsigned short* sC16 = (unsigned short*)uC;
        #pragma unroll
        for (int k = 0; k < 4; ++k) {
            int col = (wn * 4 + k) * 16 + n16;
            float bv = b1[col];
            #pragma unroll
            for (int reg = 0; reg < 4; ++reg) {
                int r = wr * 16 + quad * 4 + reg;
                sC16[r * 136 + col] = bf16_1(fmaxf(acc1[k][reg] + bv, 0.f));
            }
        }
    }
    {
        const uint4* w2p4 = (const uint4*)w2p;
        for (int j = t; j < 1024; j += 512) {
            int n = j >> 4, kp4 = j & 15;
            *(uint4*)&uB2[n * 68 + kp4 * 4] = w2p4[j];
        }
    }
    __syncthreads();

    // ---- layer 2 MFMA: rows wr*16, nt = wn*2 + {0,1} ----
    f32x4 acc2[2];
    #pragma unroll
    for (int k = 0; k < 2; ++k) acc2[k] = (f32x4){0.f, 0.f, 0.f, 0.f};
    {
        const int am = wr * 16 + n16;
        #pragma unroll
        for (int ks = 0; ks < 4; ++ks) {
            bf8_t a = *(const bf8_t*)&uC[am * 68 + ks * 16 + quad * 4];
            #pragma unroll
            for (int k = 0; k < 2; ++k) {
                int nt = wn * 2 + k;
                bf8_t b = *(const bf8_t*)&uB2[(nt * 16 + n16) * 68 + ks * 16 + quad * 4];
                acc2[k] = __builtin_amdgcn_mfma_f32_16x16x32_bf16(a, b, acc2[k], 0, 0, 0);
            }
        }
    }
    __syncthreads();   // uC/uB2 dead; out-stage overlays at offset 0

    {
        unsigned short* sA16 = (unsigned short*)smem;
        #pragma unroll
        for (int reg = 0; reg < 4; ++reg) {
            int r = wr * 16 + quad * 4 + reg;
            int row = row0 + r;
            float dd2 = (row < N) ? dinv[row] : 0.f;
            #pragma unroll
            for (int k = 0; k < 2; ++k) {
                int nt = wn * 2 + k;
                sA16[r * 72 + nt * 16 + n16] = bf16_1(acc2[k][reg] * dd2);
            }
        }
    }
    __syncthreads();
    {
        int i = t;   // exactly 512 uint4 outputs, one per thread
        int r = i >> 3, cc = i & 7;
        int row = row0 + r;
        if (row < N)
            ((uint4*)xs2b)[(size_t)row * 8 + cc] = *(uint4*)&smem[r * 36 + cc * 4];
    }
}

// ------- gather_pairs: cB[b] = [h2(u), h2(i)]; one pair/wave, DEPTH-4 pipeline -------
__global__ __launch_bounds__(256) void k_gather_pairs(const int* __restrict__ rowstart,
                                                      const int* __restrict__ csr,
                                                      const float* __restrict__ dinv,
                                                      const uint4* __restrict__ xs2b4,
                                                      const float* __restrict__ b2,
                                                      const int* __restrict__ ui,
                                                      const int* __restrict__ ii,
                                                      float* __restrict__ cB, int B) {
    const int w = threadIdx.x >> 6;
    const int b = blockIdx.x * 4 + w;
    const int l = threadIdx.x & 63;
    const int half = l >> 5;
    const int h = l & 31;
    const int sub = h >> 3;
    const int c = h & 7;
    const int hb = half * 32;
    if (b >= B) return;
    const int node = (half == 0) ? (ui[b] - 1) : (N_USERS_C + ii[b] - 1);
    const int rs = rowstart[node];
    const int re = rowstart[node + 1];
    uint4 us = xs2b4[(size_t)node * 8 + c];   // self term early
    float dd = dinv[node];

    float acc[8] = {0.f, 0.f, 0.f, 0.f, 0.f, 0.f, 0.f, 0.f};
    for (int base = rs; base < re; base += 32) {
        int idx = base + h;
        int sE = (idx < re) ? csr[idx] : 0;
        int cnt = re - base; if (cnt > 32) cnt = 32;
        int groups = (cnt + 3) >> 2;
        uint4 u0, u1, u2, u3;
        {
            int sk;
            if (0 < groups) { sk = __shfl(sE, hb + 0 + sub);  u0 = xs2b4[(size_t)sk * 8 + c]; }
            if (1 < groups) { sk = __shfl(sE, hb + 4 + sub);  u1 = xs2b4[(size_t)sk * 8 + c]; }
            if (2 < groups) { sk = __shfl(sE, hb + 8 + sub);  u2 = xs2b4[(size_t)sk * 8 + c]; }
            if (3 < groups) { sk = __shfl(sE, hb + 12 + sub); u3 = xs2b4[(size_t)sk * 8 + c]; }
        }
        for (int g = 0; g < groups; g += 4) {
            uint4 c0 = u0, c1 = u1, c2 = u2, c3 = u3;
            {
                int sk;
                if (g + 4 < groups) { sk = __shfl(sE, hb + (g + 4) * 4 + sub); u0 = xs2b4[(size_t)sk * 8 + c]; }
                if (g + 5 < groups) { sk = __shfl(sE, hb + (g + 5) * 4 + sub); u1 = xs2b4[(size_t)sk * 8 + c]; }
                if (g + 6 < groups) { sk = __shfl(sE, hb + (g + 6) * 4 + sub); u2 = xs2b4[(size_t)sk * 8 + c]; }
                if (g + 7 < groups) { sk = __shfl(sE, hb + (g + 7) * 4 + sub); u3 = xs2b4[(size_t)sk * 8 + c]; }
            }
            if ((g + 0) * 4 + sub < cnt) ACC8(c0);
            if ((g + 1) * 4 + sub < cnt) ACC8(c1);
            if ((g + 2) * 4 + sub < cnt) ACC8(c2);
            if ((g + 3) * 4 + sub < cnt) ACC8(c3);
        }
    }
    #pragma unroll
    for (int m = 8; m < 32; m <<= 1)
        #pragma unroll
        for (int i = 0; i < 8; ++i) acc[i] += __shfl_xor(acc[i], m);
    if (sub == 0) {
        float4 s0, s1;
        s0.x = bf_lo(us.x); s0.y = bf_hi(us.x); s0.z = bf_lo(us.y); s0.w = bf_hi(us.y);
        s1.x = bf_lo(us.z); s1.y = bf_hi(us.z); s1.z = bf_lo(us.w); s1.w = bf_hi(us.w);
        float4 bb0 = ((const float4*)b2)[c * 2];
        float4 bb1 = ((const float4*)b2)[c * 2 + 1];
        float4 o0, o1;
        o0.x = dd * (acc[0] + s0.x) + bb0.x;
        o0.y = dd * (acc[1] + s0.y) + bb0.y;
        o0.z = dd * (acc[2] + s0.z) + bb0.z;
        o0.w = dd * (acc[3] + s0.w) + bb0.w;
        o1.x = dd * (acc[4] + s1.x) + bb1.x;
        o1.y = dd * (acc[5] + s1.y) + bb1.y;
        o1.z = dd * (acc[6] + s1.z) + bb1.z;
        o1.w = dd * (acc[7] + s1.w) + bb1.w;
        ((float4*)cB)[(size_t)b * 32 + half * 16 + c * 2] = o0;
        ((float4*)cB)[(size_t)b * 32 + half * 16 + c * 2 + 1] = o1;
    }
}

// ---------------- fused MLP: 32 rows/block ----------------
__global__ __launch_bounds__(256) void k_mlp(const float* __restrict__ cB,
                                             const float* __restrict__ fcW1, const float* __restrict__ fcb1,
                                             const float* __restrict__ g1,   const float* __restrict__ be1,
                                             const float* __restrict__ fcW2, const float* __restrict__ fcb2,
                                             const float* __restrict__ g2,   const float* __restrict__ be2,
                                             const float* __restrict__ fcW3, const float* __restrict__ fcb3,
                                             float* __restrict__ out) {
    __shared__ float sIn[32 * 128];
    __shared__ float sW[64 * 128];
    const int t = threadIdx.x;
    const int row0 = blockIdx.x * 32;
    const int rg = t >> 4;
    const int cg = t & 15;

    for (int i = t; i < 1024; i += 256) {
        int r = i >> 5, c4 = i & 31;
        *(float4*)&sIn[r * 128 + c4 * 4] = *(const float4*)&cB[(size_t)(row0 + r) * 128 + c4 * 4];
    }

    float acc1[2][8];
    {
        float4 b01 = *(const float4*)&fcb1[cg * 8];
        float4 b23 = *(const float4*)&fcb1[cg * 8 + 4];
        #pragma unroll
        for (int jj = 0; jj < 2; ++jj) {
            acc1[jj][0] = b01.x; acc1[jj][1] = b01.y; acc1[jj][2] = b01.z; acc1[jj][3] = b01.w;
            acc1[jj][4] = b23.x; acc1[jj][5] = b23.y; acc1[jj][6] = b23.z; acc1[jj][7] = b23.w;
        }
    }
    for (int s = 0; s < 2; ++s) {
        __syncthreads();
        for (int i = t; i < 2048; i += 256) {
            int k = i >> 5, c4 = i & 31;
            *(float4*)&sW[k * 128 + c4 * 4] = *(const float4*)&fcW1[(size_t)(64 * s + k) * 128 + c4 * 4];
        }
        __syncthreads();
        for (int k0 = 0; k0 < 64; k0 += 4) {
            float4 a[2];
            #pragma unroll
            for (int jj = 0; jj < 2; ++jj)
                a[jj] = *(const float4*)&sIn[(rg * 2 + jj) * 128 + 64 * s + k0];
            #pragma unroll
            for (int kk = 0; kk < 4; ++kk) {
                float4 w0 = *(const float4*)&sW[(k0 + kk) * 128 + cg * 8];
                float4 w1 = *(const float4*)&sW[(k0 + kk) * 128 + cg * 8 + 4];
                #pragma unroll
                for (int jj = 0; jj < 2; ++jj) {
                    float f = ((const float*)&a[jj])[kk];
                    acc1[jj][0] += f * w0.x; acc1[jj][1] += f * w0.y;
                    acc1[jj][2] += f * w0.z; acc1[jj][3] += f * w0.w;
                    acc1[jj][4] += f * w1.x; acc1[jj][5] += f * w1.y;
                    acc1[jj][6] += f * w1.z; acc1[jj][7] += f * w1.w;
                }
            }
        }
    }
    __syncthreads();

    {
        float4 g01 = *(const float4*)&g1[cg * 8];
        float4 g23 = *(const float4*)&g1[cg * 8 + 4];
        float4 e01 = *(const float4*)&be1[cg * 8];
        float4 e23 = *(const float4*)&be1[cg * 8 + 4];
        float gv[8] = {g01.x, g01.y, g01.z, g01.w, g23.x, g23.y, g23.z, g23.w};
        float ev[8] = {e01.x, e01.y, e01.z, e01.w, e23.x, e23.y, e23.z, e23.w};
        #pragma unroll
        for (int jj = 0; jj < 2; ++jj) {
            float s_ = 0.f, ss = 0.f;
            #pragma unroll
            for (int c = 0; c < 8; ++c) { float v = acc1[jj][c]; s_ += v; ss += v * v; }
            #pragma unroll
            for (int m = 1; m < 16; m <<= 1) { s_ += __shfl_xor(s_, m); ss += __shfl_xor(ss, m); }
            float mu = s_ * (1.0f / 128.0f);
            float var = ss * (1.0f / 128.0f) - mu * mu;
            float rs = rsqrtf(var + 1e-5f);
            #pragma unroll
            for (int c = 0; c < 8; ++c) {
                float z = (acc1[jj][c] - mu) * rs * gv[c] + ev[c];
                sIn[(rg * 2 + jj) * 128 + cg * 8 + c] = fmaxf(z, 0.f);
            }
        }
    }
    __syncthreads();

    for (int i = t; i < 2048; i += 256) {
        int k = i >> 4, c4 = i & 15;
        *(float4*)&sW[k * 64 + c4 * 4] = *(const float4*)&fcW2[(size_t)k * 64 + c4 * 4];
    }
    float acc2[2][4];
    {
        float4 bv = *(const float4*)&fcb2[cg * 4];
        #pragma unroll
        for (int jj = 0; jj < 2; ++jj) {
            acc2[jj][0] = bv.x; acc2[jj][1] = bv.y; acc2[jj][2] = bv.z; acc2[jj][3] = bv.w;
        }
    }
    __syncthreads();
    for (int k0 = 0; k0 < 128; k0 += 4) {
        float4 a[2], w[4];
        #pragma unroll
        for (int jj = 0; jj < 2; ++jj) a[jj] = *(const float4*)&sIn[(rg * 2 + jj) * 128 + k0];
        #pragma unroll
        for (int kk = 0; kk < 4; ++kk) w[kk] = *(const float4*)&sW[(k0 + kk) * 64 + cg * 4];
        #pragma unroll
        for (int jj = 0; jj < 2; ++jj) {
            const float* aj = (const float*)&a[jj];
            #pragma unroll
            for (int kk = 0; kk < 4; ++kk) {
                float f = aj[kk];
                acc2[jj][0] += f * w[kk].x; acc2[jj][1] += f * w[kk].y;
                acc2[jj][2] += f * w[kk].z; acc2[jj][3] += f * w[kk].w;
            }
        }
    }

    {
        float4 gv4 = *(const float4*)&g2[cg * 4];
        float4 ev4 = *(const float4*)&be2[cg * 4];
        float4 w34 = *(const float4*)&fcW3[cg * 4];
        float gv[4] = {gv4.x, gv4.y, gv4.z, gv4.w};
        float ev[4] = {ev4.x, ev4.y, ev4.z, ev4.w};
        float wv[4] = {w34.x, w34.y, w34.z, w34.w};
        float b3 = fcb3[0];
        #pragma unroll
        for (int jj = 0; jj < 2; ++jj) {
            float s_ = 0.f, ss = 0.f;
            #pragma unroll
            for (int c = 0; c < 4; ++c) { float v = acc2[jj][c]; s_ += v; ss += v * v; }
            #pragma unroll
            for (int m = 1; m < 16; m <<= 1) { s_ += __shfl_xor(s_, m); ss += __shfl_xor(ss, m); }
            float mu = s_ * (1.0f / 64.0f);
            float var = ss * (1.0f / 64.0f) - mu * mu;
            float rs = rsqrtf(var + 1e-5f);
            float p = 0.f;
            #pragma unroll
            for (int c = 0; c < 4; ++c) {
                float z = fmaxf((acc2[jj][c] - mu) * rs * gv[c] + ev[c], 0.f);
                p += z * wv[c];
            }
            #pragma unroll
            for (int m = 1; m < 16; m <<= 1) p += __shfl_xor(p, m);
            if (cg == 0) out[row0 + rg * 2 + jj] = 1.0f / (1.0f + expf(-(p + b3)));
        }
    }
}

extern "C" void kernel_launch(void* const* d_in, const int* in_sizes, int n_in,
                              void* d_out, int out_size, void* d_ws, size_t ws_size,
                              hipStream_t stream) {
    const float* x    = (const float*)d_in[0];
    const int*   src  = (const int*)d_in[1];
    const int*   dst  = (const int*)d_in[2];
    const int*   ui   = (const int*)d_in[3];
    const int*   ii   = (const int*)d_in[4];
    const float* W1   = (const float*)d_in[5];
    const float* b1   = (const float*)d_in[6];
    const float* W2   = (const float*)d_in[7];
    const float* b2   = (const float*)d_in[8];
    const float* fcW1 = (const float*)d_in[9];
    const float* fcb1 = (const float*)d_in[10];
    const float* g1   = (const float*)d_in[11];
    const float* be1  = (const float*)d_in[12];
    const float* fcW2 = (const float*)d_in[13];
    const float* fcb2 = (const float*)d_in[14];
    const float* g2   = (const float*)d_in[15];
    const float* be2  = (const float*)d_in[16];
    const float* fcW3 = (const float*)d_in[17];
    const float* fcb3 = (const float*)d_in[18];
    float* out = (float*)d_out;

    const int N = in_sizes[0] / 64;          // 150000
    const int E = in_sizes[1];               // 2400000
    const int B = in_sizes[3];               // 16384
    const int NBK = (N + BK_NODES - 1) >> BK_SHIFT;   // 293
    const int EB2 = (E + 4095) / 4096;       // 586 (hist blocks)
    const int n2 = N * 32;
    const int XB = (n2 + 2047) / 2048;

    // ---- workspace layout (~77 MB) ----
    float* ws   = (float*)d_ws;
    float* dinv = ws;                                   // N
    int* rowstart = (int*)(dinv + N);                   // N+1
    int* csr      = rowstart + (N + 1);                 // E
    unsigned int* xb = (unsigned int*)(csr + E);        // N*32 (bf16 x, pre-scaled by dinv after bscatter)
    unsigned int* bufU = xb + (size_t)N * 32;           // N*32: CSR scratch
    unsigned int* xs2b = bufU + (size_t)N * 32;         // N*32 (bf16 xs2)
    float* cB = (float*)(xs2b + (size_t)N * 32);        // B*128 f32
    unsigned int* w1p = (unsigned int*)(cB + (size_t)B * 128);  // 4096 (packed W1T) - outside bufU!
    unsigned int* w2p = w1p + 4096;                     // 4096 (packed W2T)
    int* pairBuf = (int*)bufU;                          // E
    int* chist   = pairBuf + E;                         // 512*CPAD (line-padded)
    int* bcursor = chist + 512 * CPAD;                  // 512*CPAD (adjacent: one memset)

    // ---- CSR build + bf16 conversion + weight pre-pack ----
    hipMemsetAsync(chist, 0, 2 * 512 * CPAD * sizeof(int), stream);   // chist + bcursor
    k_pre<<<EB2 + XB + 2, 512, 0, stream>>>(dst, chist, x, xb, W1, W2, w1p, w2p,
                                            E, NBK, EB2, n2, XB);
    k_bin<<<EB2, 512, 0, stream>>>(src, dst, chist, bcursor, pairBuf, E, NBK);
    k_bscatter<<<NBK, 512, 0, stream>>>(pairBuf, chist, rowstart, dinv, csr, xb, N, E, NBK);

    // ---- fused gather1 + layer1 + layer2 (512 thr, 34.8KB LDS, spill-free -> 4 blk/CU) ----
    k_gl12<<<(N + 63) / 64, 512, 0, stream>>>(rowstart, csr, dinv, (const uint4*)xb,
                                              w1p, b1, w2p, xs2b, N);

    // ---- pruned gather2 + concat (1 pair per wave, depth-4 pipeline) ----
    k_gather_pairs<<<(B + 3) / 4, 256, 0, stream>>>(rowstart, csr, dinv, (const uint4*)xs2b,
                                                    b2, ui, ii, cB, B);

    // ---- fused MLP ----
    k_mlp<<<B / 32, 256, 0, stream>>>(cB, fcW1, fcb1, g1, be1,
                                      fcW2, fcb2, g2, be2, fcW3, fcb3, out);
}